// Round 2
// baseline (234.147 us; speedup 1.0000x reference)
//
#include <hip/hip_runtime.h>

// Problem constants (fixed by setup_inputs): B=8, S=4096, H=1024
constexpr int Bn  = 8;
constexpr int Sn  = 4096;
constexpr int Nn  = Bn * Sn;          // 32768 labels
constexpr int Hn  = 1024;

constexpr size_t FEAT_ELEMS = (size_t)Nn * Hn;   // 33,554,432 floats
constexpr size_t FEAT_BYTES = FEAT_ELEMS * sizeof(float);  // 128 MiB

constexpr int STPB  = 1024;           // scan block size (16 waves)
constexpr int SNW   = STPB / 64;      // 16 waves
constexpr int G4    = Nn / 4;         // 8192 int4 label groups
constexpr int TILES = G4 / STPB;      // 8 coalesced tiles

typedef float v4f __attribute__((ext_vector_type(4)));

// Standalone segment-id scan: one block, 1024 threads, 8 coalesced tiles.
// Per tile: each thread owns one int4 group (4 labels); wave-level shfl scan
// + per-thread sum of the 16 wave totals (LDS broadcast reads) + running
// carry across tiles. Next tile's load is prefetched before the scan to hide
// L2/HBM latency. Segment ids (max ~16.4k) are exact in fp32.
__global__ __launch_bounds__(STPB) void seg_kernel(const int* __restrict__ labels,
                                                   float* __restrict__ out) {
    __shared__ int wsums[SNW];
    __shared__ int extra_sh[Bn];

    const int tid  = threadIdx.x;
    const int lane = tid & 63;
    const int wave = tid >> 6;

    const int4* __restrict__ lab4 = reinterpret_cast<const int4*>(labels);
    v4f* __restrict__ seg4 = reinterpret_cast<v4f*>(out + FEAT_ELEMS);

    // Tiny serial job: exclusive scan of the 8 per-example "extra" bits
    // (8 independent loads, issued together; overlaps other threads' prefetch)
    if (tid == 0) {
        int acc = 0;
#pragma unroll
        for (int b = 0; b < Bn; ++b) {
            extra_sh[b] = acc;
            acc += (labels[b * Sn + Sn - 1] == 1);
        }
    }

    int carry = 0;
    int4 v = lab4[tid];               // prefetch tile 0
    __syncthreads();                  // extra_sh ready

    for (int k = 0; k < TILES; ++k) {
        int4 nv;
        if (k + 1 < TILES) nv = lab4[(k + 1) * STPB + tid];   // prefetch next

        const int f0 = (v.x == 0), f1 = (v.y == 0), f2 = (v.z == 0), f3 = (v.w == 0);
        const int c = f0 + f1 + f2 + f3;

        // wave64 inclusive scan of per-thread zero counts
        int incl = c;
#pragma unroll
        for (int off = 1; off < 64; off <<= 1) {
            int u = __shfl_up(incl, off, 64);
            if (lane >= off) incl += u;
        }
        if (lane == 63) wsums[wave] = incl;
        __syncthreads();

        // per-thread: exclusive sum of earlier waves + tile total
        // (same-address LDS reads broadcast — conflict-free)
        int wexcl = 0, tot = 0;
#pragma unroll
        for (int w = 0; w < SNW; ++w) {
            int s = wsums[w];
            wexcl += (w < wave) ? s : 0;
            tot   += s;
        }

        const int g    = k * STPB + tid;          // int4 group index
        const int base = carry + wexcl + (incl - c) + extra_sh[g >> 10];
        v4f r;
        r.x = (float)base;
        r.y = (float)(base + f0);
        r.z = (float)(base + f0 + f1);
        r.w = (float)(base + f0 + f1 + f2);
        __builtin_nontemporal_store(r, &seg4[g]);

        carry += tot;
        __syncthreads();              // wsums reusable next tile
        v = nv;
    }
}

extern "C" void kernel_launch(void* const* d_in, const int* in_sizes, int n_in,
                              void* d_out, int out_size, void* d_ws, size_t ws_size,
                              hipStream_t stream) {
    const float* seq    = (const float*)d_in[0];  // [B,S,H] fp32
    const int*   labels = (const int*)d_in[1];    // [B,S] int32 (harness-delivered)
    float*       out    = (float*)d_out;

    // 1) tiny seg-id scan (128 KiB out), one block
    seg_kernel<<<1, STPB, 0, stream>>>(labels, out);

    // 2) bulk feature copy: vendor-tuned D2D blit (graph-capture-safe per
    //    harness rules: hipMemcpyAsync on the provided stream is allowed)
    hipMemcpyAsync(out, seq, FEAT_BYTES, hipMemcpyDeviceToDevice, stream);
}